// Round 1
// baseline (1119.022 us; speedup 1.0000x reference)
//
#include <hip/hip_runtime.h>
#include <hip/hip_bf16.h>
#include <cstdint>

// Problem constants
#define BATCH 128
#define SEQ   512
#define EMB   300
#define HID   100
#define G3    300   // 3*HID
#define NCLS  20
#define NROWS (SEQ * BATCH)  // 65536

// ---------------- threefry2x32 (JAX-compatible) ----------------
__host__ __device__ __forceinline__ void threefry2x32(uint32_t k0, uint32_t k1,
                                                      uint32_t x0, uint32_t x1,
                                                      uint32_t* o0, uint32_t* o1) {
  uint32_t ks2 = k0 ^ k1 ^ 0x1BD11BDAu;
  x0 += k0; x1 += k1;
#define TFR(r) { x0 += x1; x1 = (x1 << (r)) | (x1 >> (32 - (r))); x1 ^= x0; }
  TFR(13) TFR(15) TFR(26) TFR(6)  x0 += k1;  x1 += ks2 + 1u;
  TFR(17) TFR(29) TFR(16) TFR(24) x0 += ks2; x1 += k0 + 2u;
  TFR(13) TFR(15) TFR(26) TFR(6)  x0 += k0;  x1 += k1 + 3u;
  TFR(17) TFR(29) TFR(16) TFR(24) x0 += k1;  x1 += ks2 + 4u;
  TFR(13) TFR(15) TFR(26) TFR(6)  x0 += ks2; x1 += k0 + 5u;
#undef TFR
  *o0 = x0; *o1 = x1;
}

// partitionable random_bits(32): bits = o0 ^ o1 with ctr = (0, flat_idx)
__device__ __forceinline__ uint32_t rand_bits32(uint32_t ka, uint32_t kb, uint32_t flat) {
  uint32_t a, b;
  threefry2x32(ka, kb, 0u, flat, &a, &b);
  return a ^ b;
}

// ---------------- K1: GI = dropout1(emb[idx]) @ w_ih^T + b_ih ----------------
// grid 1024 blocks (64 rows each), 320 threads; row index = s*128 + b
__global__ __launch_bounds__(320) void k_gi(const int* __restrict__ inputs,
                                            const float* __restrict__ emb,
                                            const float* __restrict__ w_ih,
                                            const float* __restrict__ b_ih,
                                            float* __restrict__ GI,
                                            uint32_t k1a, uint32_t k1b) {
  __shared__ __align__(16) float Xs[64][100];
  const int t = threadIdx.x;
  const int r0 = blockIdx.x * 64;
  const int s = r0 >> 7;          // block covers one s (64 | 128)
  const int bbase = r0 & 127;     // 0 or 64

  float acc[64];
#pragma unroll
  for (int r = 0; r < 64; ++r) acc[r] = 0.f;

  for (int kc = 0; kc < EMB; kc += 100) {
    __syncthreads();  // protect Xs from previous chunk's readers
    // stage 64x100 chunk of X with gather + dropout1
    for (int j = t; j < 6400; j += 320) {
      int r = j / 100;
      int k = j - r * 100;
      int b = bbase + r;
      int idx = inputs[b * SEQ + s];
      int e = kc + k;
      uint32_t fl = (uint32_t)((b * SEQ + s) * EMB + e);   // m1 flat index [B,S,E]
      uint32_t bits = rand_bits32(k1a, k1b, fl);
      float v = (bits >> 31) ? 0.f : emb[idx * EMB + e] * 2.0f;  // /keep = *2
      Xs[r][k] = v;
    }
    __syncthreads();
    if (t < G3) {
      for (int kq = 0; kq < 100; kq += 4) {
        float4 w4 = *(const float4*)(w_ih + t * EMB + kc + kq);
#pragma unroll
        for (int r = 0; r < 64; ++r) {
          float4 x4 = *(const float4*)(&Xs[r][kq]);
          acc[r] += x4.x * w4.x + x4.y * w4.y + x4.z * w4.z + x4.w * w4.w;
        }
      }
    }
  }
  if (t < G3) {
    float bb = b_ih[t];
    for (int r = 0; r < 64; ++r)
      GI[(size_t)(r0 + r) * G3 + t] = acc[r] + bb;
  }
}

// ---------------- K2: sequential GRU recurrence, one block per batch ----------------
__global__ __launch_bounds__(320, 1) void k_rnn(const float* __restrict__ GI,
                                                const float* __restrict__ w_hh,
                                                const float* __restrict__ b_hh,
                                                float* __restrict__ Hd,
                                                uint32_t k2a, uint32_t k2b) {
  __shared__ __align__(16) float h_s[HID];
  __shared__ float A_s[G3];   // gi (includes b_ih from K1)
  __shared__ float Bh_s[G3];  // gh = h @ w_hh^T + b_hh
  const int t = threadIdx.x;
  const int b = blockIdx.x;

  float w[HID];
  float bhh = 0.f;
  if (t < G3) {
#pragma unroll
    for (int k = 0; k < HID; k += 4) {
      float4 w4 = *(const float4*)(w_hh + t * HID + k);
      w[k] = w4.x; w[k + 1] = w4.y; w[k + 2] = w4.z; w[k + 3] = w4.w;
    }
    bhh = b_hh[t];
  }
  if (t < HID) h_s[t] = 0.f;
  float g = (t < G3) ? GI[(size_t)(0 * BATCH + b) * G3 + t] : 0.f;
  __syncthreads();

  for (int s = 0; s < SEQ; ++s) {
    // prefetch next step's gi row (hides L2/L3 latency behind the dot)
    float gnext = 0.f;
    if (t < G3 && s + 1 < SEQ) gnext = GI[(size_t)((s + 1) * BATCH + b) * G3 + t];

    if (t < G3) {
      float acc = 0.f;
#pragma unroll
      for (int k = 0; k < HID; k += 4) {
        float4 h4 = *(const float4*)(&h_s[k]);   // wave-uniform broadcast
        acc += w[k] * h4.x + w[k + 1] * h4.y + w[k + 2] * h4.z + w[k + 3] * h4.w;
      }
      A_s[t] = g;
      Bh_s[t] = acc + bhh;
    }
    __syncthreads();   // all dots done; A/Bh visible
    if (t < HID) {
      float ir = A_s[t],       hr = Bh_s[t];
      float iz = A_s[t + 100], hz = Bh_s[t + 100];
      float in_ = A_s[t + 200], hn = Bh_s[t + 200];
      float r = 1.f / (1.f + __expf(-(ir + hr)));
      float z = 1.f / (1.f + __expf(-(iz + hz)));
      float n = tanhf(in_ + r * hn);
      float hnew = (1.f - z) * n + z * h_s[t];
      uint32_t fl = (uint32_t)((s * BATCH + b) * HID + t);  // m2 flat [S,B,H]
      uint32_t bits = rand_bits32(k2a, k2b, fl);
      float hd = (bits >> 31) ? 0.f : hnew * 2.f;
      Hd[(size_t)(b * SEQ + s) * HID + t] = hd;   // layout [B][S][H]
      h_s[t] = hnew;
    }
    __syncthreads();   // h update visible before next step's dots
    g = gnext;
  }
}

// ---------------- K3: logits + log_softmax, thread per (b,s) ----------------
__global__ __launch_bounds__(256) void k_out(const float* __restrict__ Hd,
                                             const float* __restrict__ w_lin,
                                             const float* __restrict__ b_lin,
                                             float* __restrict__ out) {
  int gid = blockIdx.x * 256 + threadIdx.x;  // gid = b*512 + s
  if (gid >= NROWS) return;
  int b = gid >> 9;
  int s = gid & 511;
  float acc[NCLS];
#pragma unroll
  for (int c = 0; c < NCLS; ++c) acc[c] = b_lin[c];
  for (int k = 0; k < HID; k += 4) {
    float4 h4 = *(const float4*)(Hd + (size_t)gid * HID + k);
#pragma unroll
    for (int c = 0; c < NCLS; ++c) {
      float4 w4 = *(const float4*)(w_lin + c * HID + k);  // uniform -> s_load
      acc[c] += h4.x * w4.x + h4.y * w4.y + h4.z * w4.z + h4.w * w4.w;
    }
  }
  float mx = acc[0];
#pragma unroll
  for (int c = 1; c < NCLS; ++c) mx = fmaxf(mx, acc[c]);
  float se = 0.f;
#pragma unroll
  for (int c = 0; c < NCLS; ++c) se += __expf(acc[c] - mx);
  float lse = mx + __logf(se);
#pragma unroll
  for (int c = 0; c < NCLS; ++c)
    out[(size_t)b * (NCLS * SEQ) + c * SEQ + s] = acc[c] - lse;
}

// ---------------- host ----------------
extern "C" void kernel_launch(void* const* d_in, const int* in_sizes, int n_in,
                              void* d_out, int out_size, void* d_ws, size_t ws_size,
                              hipStream_t stream) {
  const int*   inputs = (const int*)d_in[0];
  const float* emb    = (const float*)d_in[1];
  const float* w_ih   = (const float*)d_in[2];
  const float* w_hh   = (const float*)d_in[3];
  const float* b_ih   = (const float*)d_in[4];
  const float* b_hh   = (const float*)d_in[5];
  const float* w_lin  = (const float*)d_in[6];
  const float* b_lin  = (const float*)d_in[7];
  float* out = (float*)d_out;

  float* GI = (float*)d_ws;                         // 65536*300 f32 = 78.6 MB
  float* Hd = GI + (size_t)NROWS * G3;              // 65536*100 f32 = 26.2 MB

  // JAX: dk1, dk2 = split(key(42)) under threefry_partitionable:
  //   dk_i = threefry2x32((0,42), (0, i))
  uint32_t dk1a, dk1b, dk2a, dk2b;
  threefry2x32(0u, 42u, 0u, 0u, &dk1a, &dk1b);
  threefry2x32(0u, 42u, 0u, 1u, &dk2a, &dk2b);

  k_gi<<<NROWS / 64, 320, 0, stream>>>(inputs, emb, w_ih, b_ih, GI, dk1a, dk1b);
  k_rnn<<<BATCH, 320, 0, stream>>>(GI, w_hh, b_hh, Hd, dk2a, dk2b);
  k_out<<<NROWS / 256, 256, 0, stream>>>(Hd, w_lin, b_lin, out);
}

// Round 3
// 1054.278 us; speedup vs baseline: 1.0614x; 1.0614x over previous
//
#include <hip/hip_runtime.h>
#include <hip/hip_bf16.h>
#include <cstdint>

#define BATCH 128
#define SEQ   512
#define EMB   300
#define HID   100
#define G3    300
#define NCLS  20
#define NROWS (SEQ * BATCH)

// ---------------- threefry2x32 (JAX-compatible, verified round 1) ----------------
__host__ __device__ __forceinline__ void threefry2x32(uint32_t k0, uint32_t k1,
                                                      uint32_t x0, uint32_t x1,
                                                      uint32_t* o0, uint32_t* o1) {
  uint32_t ks2 = k0 ^ k1 ^ 0x1BD11BDAu;
  x0 += k0; x1 += k1;
#define TFR(r) { x0 += x1; x1 = (x1 << (r)) | (x1 >> (32 - (r))); x1 ^= x0; }
  TFR(13) TFR(15) TFR(26) TFR(6)  x0 += k1;  x1 += ks2 + 1u;
  TFR(17) TFR(29) TFR(16) TFR(24) x0 += ks2; x1 += k0 + 2u;
  TFR(13) TFR(15) TFR(26) TFR(6)  x0 += k0;  x1 += k1 + 3u;
  TFR(17) TFR(29) TFR(16) TFR(24) x0 += k1;  x1 += ks2 + 4u;
  TFR(13) TFR(15) TFR(26) TFR(6)  x0 += ks2; x1 += k0 + 5u;
#undef TFR
  *o0 = x0; *o1 = x1;
}

__device__ __forceinline__ uint32_t rand_bits32(uint32_t ka, uint32_t kb, uint32_t flat) {
  uint32_t a, b;
  threefry2x32(ka, kb, 0u, flat, &a, &b);
  return a ^ b;
}

// ---------------- K1: GI = dropout1(emb[idx]) @ w_ih^T + b_ih ----------------
// 128x128 tile, 8x8 per thread, K padded to 304 (chunks of 16).
// grid (512 s-tiles, 3 n-tiles), block 256.  [unchanged from round 2]
__global__ __launch_bounds__(256) void k_gi2(const int* __restrict__ inputs,
                                             const float* __restrict__ emb,
                                             const float* __restrict__ w_ih,
                                             const float* __restrict__ b_ih,
                                             float* __restrict__ GI,
                                             uint32_t k1a, uint32_t k1b) {
  __shared__ float Xs[16][132];   // [k][m]; byte stride 528 = 16*33 keeps float4 alignment
  __shared__ float Ws[16][132];   // [k][n]
  __shared__ int idxs[128];
  const int t = threadIdx.x;
  const int s = blockIdx.x;
  const int n0 = blockIdx.y * 128;
  const int tx = t & 15, ty = t >> 4;

  if (t < 128) idxs[t] = inputs[t * SEQ + s];

  float acc[8][8];
#pragma unroll
  for (int i = 0; i < 8; ++i)
#pragma unroll
    for (int j = 0; j < 8; ++j) acc[i][j] = 0.f;

  __syncthreads();

  for (int kc = 0; kc < 304; kc += 16) {
#pragma unroll
    for (int half = 0; half < 2; ++half) {
      int fi = t + half * 256;          // 0..511
      int row = fi >> 2;                // 0..127
      int kq = fi & 3;
      int e0 = kc + kq * 4;
      float4 xv = make_float4(0.f, 0.f, 0.f, 0.f);
      if (e0 < 300) {
        xv = *(const float4*)(emb + (size_t)idxs[row] * EMB + e0);
        uint32_t base = (uint32_t)((row * SEQ + s) * EMB + e0);
        xv.x = (rand_bits32(k1a, k1b, base + 0u) >> 31) ? 0.f : xv.x * 2.f;
        xv.y = (rand_bits32(k1a, k1b, base + 1u) >> 31) ? 0.f : xv.y * 2.f;
        xv.z = (rand_bits32(k1a, k1b, base + 2u) >> 31) ? 0.f : xv.z * 2.f;
        xv.w = (rand_bits32(k1a, k1b, base + 3u) >> 31) ? 0.f : xv.w * 2.f;
      }
      Xs[kq * 4 + 0][row] = xv.x;
      Xs[kq * 4 + 1][row] = xv.y;
      Xs[kq * 4 + 2][row] = xv.z;
      Xs[kq * 4 + 3][row] = xv.w;
      int n = n0 + row;
      float4 wv = make_float4(0.f, 0.f, 0.f, 0.f);
      if (e0 < 300 && n < 300) wv = *(const float4*)(w_ih + (size_t)n * EMB + e0);
      Ws[kq * 4 + 0][row] = wv.x;
      Ws[kq * 4 + 1][row] = wv.y;
      Ws[kq * 4 + 2][row] = wv.z;
      Ws[kq * 4 + 3][row] = wv.w;
    }
    __syncthreads();
#pragma unroll
    for (int k = 0; k < 16; ++k) {
      float4 xa = *(const float4*)&Xs[k][ty * 4];
      float4 xb = *(const float4*)&Xs[k][64 + ty * 4];
      float4 wa = *(const float4*)&Ws[k][tx * 4];
      float4 wb = *(const float4*)&Ws[k][64 + tx * 4];
      float xs8[8] = {xa.x, xa.y, xa.z, xa.w, xb.x, xb.y, xb.z, xb.w};
      float ws8[8] = {wa.x, wa.y, wa.z, wa.w, wb.x, wb.y, wb.z, wb.w};
#pragma unroll
      for (int i = 0; i < 8; ++i)
#pragma unroll
        for (int j = 0; j < 8; ++j) acc[i][j] = fmaf(xs8[i], ws8[j], acc[i][j]);
    }
    __syncthreads();
  }

#pragma unroll
  for (int i = 0; i < 8; ++i) {
    int m = (i < 4) ? (ty * 4 + i) : (64 + ty * 4 + (i - 4));
    size_t rbase = (size_t)(s * BATCH + m) * G3;
    int cA = n0 + tx * 4;
    int cB = n0 + 64 + tx * 4;
    if (cA < 300) {
      float4 o = make_float4(acc[i][0] + b_ih[cA], acc[i][1] + b_ih[cA + 1],
                             acc[i][2] + b_ih[cA + 2], acc[i][3] + b_ih[cA + 3]);
      *(float4*)(GI + rbase + cA) = o;
    }
    if (cB < 300) {
      float4 o = make_float4(acc[i][4] + b_ih[cB], acc[i][5] + b_ih[cB + 1],
                             acc[i][6] + b_ih[cB + 2], acc[i][7] + b_ih[cB + 3]);
      *(float4*)(GI + rbase + cB) = o;
    }
  }
}

// ---------------- K2: GRU recurrence — readlane broadcast, UNIFORM dot phase ----------------
// 128 blocks (one per batch), 192 threads (3 waves).
// FIX vs round 2: the h loads + readlane dot run in straight-line code for ALL
// threads (no divergent branch), so the compiler cannot sink the hA/hB
// definitions away from wave-2 lanes 22..63 that readlane sources from.
// Threads t>=150 compute a redundant clamped row; only the Bh_s stores are
// predicated.
__global__ __launch_bounds__(192, 1) void k_rnn(const float* __restrict__ GI,
                                                const float* __restrict__ w_hh,
                                                const float* __restrict__ b_hh,
                                                float* __restrict__ Hd,
                                                uint32_t k2a, uint32_t k2b) {
  __shared__ float h_s[128];
  __shared__ float Bh_s[304];
  const int t = threadIdx.x;
  const int lane = t & 63;
  const int b = blockIdx.x;
  const int rA = t;                                    // 0..191, valid row
  const int rB = (t + 150 < 300) ? (t + 150) : 299;    // clamp for t>=150

  float w0[100], w1[100];
#pragma unroll
  for (int k = 0; k < 100; k += 4) {
    float4 a = *(const float4*)(w_hh + (size_t)rA * HID + k);
    w0[k] = a.x; w0[k + 1] = a.y; w0[k + 2] = a.z; w0[k + 3] = a.w;
    float4 c = *(const float4*)(w_hh + (size_t)rB * HID + k);
    w1[k] = c.x; w1[k + 1] = c.y; w1[k + 2] = c.z; w1[k + 3] = c.w;
  }
  const float bhh0 = b_hh[rA];
  const float bhh1 = b_hh[rB];
  if (t < 128) h_s[t] = 0.f;
  __syncthreads();

  for (int s = 0; s < SEQ; ++s) {
    const float* gi_row = GI + (size_t)(s * BATCH + b) * G3;
    float gr = 0.f, gz = 0.f, gn = 0.f;
    if (t < 100) {  // issue early; consumed after the barrier (no cross-lane use)
      gr = gi_row[t];
      gz = gi_row[t + 100];
      gn = gi_row[t + 200];
    }
    // uniform control flow from here to the stores:
    float hA = h_s[lane];
    float hB = h_s[64 + lane];
    float a0[4] = {0.f, 0.f, 0.f, 0.f};
    float a1[4] = {0.f, 0.f, 0.f, 0.f};
#pragma unroll
    for (int k = 0; k < 100; ++k) {
      float hk = (k < 64)
          ? __int_as_float(__builtin_amdgcn_readlane(__float_as_int(hA), k))
          : __int_as_float(__builtin_amdgcn_readlane(__float_as_int(hB), k - 64));
      a0[k & 3] = fmaf(hk, w0[k], a0[k & 3]);
      a1[k & 3] = fmaf(hk, w1[k], a1[k & 3]);
    }
    if (t < 150) {
      Bh_s[t]       = (a0[0] + a0[1]) + (a0[2] + a0[3]) + bhh0;
      Bh_s[t + 150] = (a1[0] + a1[1]) + (a1[2] + a1[3]) + bhh1;
    }
    __syncthreads();
    if (t < 100) {
      float hr = Bh_s[t], hz = Bh_s[t + 100], hn = Bh_s[t + 200];
      float r = 1.f / (1.f + __expf(-(gr + hr)));
      float z = 1.f / (1.f + __expf(-(gz + hz)));
      float xn = gn + r * hn;
      float ax = fabsf(xn);
      float e2 = __expf(2.f * ax);
      float n = copysignf(1.f - 2.f / (e2 + 1.f), xn);   // tanh, overflow-safe
      float hprev = h_s[t];
      float hnew = (1.f - z) * n + z * hprev;
      uint32_t fl = (uint32_t)((s * BATCH + b) * HID + t);
      uint32_t bits = rand_bits32(k2a, k2b, fl);
      float hd = (bits >> 31) ? 0.f : hnew * 2.f;
      Hd[(size_t)(b * SEQ + s) * HID + t] = hd;
      h_s[t] = hnew;
    }
    __syncthreads();
  }
}

// ---------------- K3: logits + log_softmax ----------------
// 256 blocks x 64 threads; each thread 4 consecutive rows; w_lin in LDS.
// [unchanged from round 2]
__global__ __launch_bounds__(64) void k_out(const float* __restrict__ Hd,
                                            const float* __restrict__ w_lin,
                                            const float* __restrict__ b_lin,
                                            float* __restrict__ out) {
  __shared__ float Wl[NCLS * HID];  // 8 KB
  __shared__ float bl[NCLS];
  const int t = threadIdx.x;
  for (int i = t; i < NCLS * HID; i += 64) Wl[i] = w_lin[i];
  if (t < NCLS) bl[t] = b_lin[t];
  __syncthreads();

  const int r0 = (blockIdx.x * 64 + t) * 4;  // 4 rows: same b, s0..s0+3
  float acc[4][NCLS];
#pragma unroll
  for (int r = 0; r < 4; ++r)
#pragma unroll
    for (int c = 0; c < NCLS; ++c) acc[r][c] = bl[c];

  for (int k = 0; k < HID; k += 4) {
    float4 h0 = *(const float4*)(Hd + (size_t)(r0 + 0) * HID + k);
    float4 h1 = *(const float4*)(Hd + (size_t)(r0 + 1) * HID + k);
    float4 h2 = *(const float4*)(Hd + (size_t)(r0 + 2) * HID + k);
    float4 h3 = *(const float4*)(Hd + (size_t)(r0 + 3) * HID + k);
#pragma unroll
    for (int c = 0; c < NCLS; ++c) {
      float4 w4 = *(const float4*)&Wl[c * HID + k];  // broadcast
      acc[0][c] += h0.x * w4.x + h0.y * w4.y + h0.z * w4.z + h0.w * w4.w;
      acc[1][c] += h1.x * w4.x + h1.y * w4.y + h1.z * w4.z + h1.w * w4.w;
      acc[2][c] += h2.x * w4.x + h2.y * w4.y + h2.z * w4.z + h2.w * w4.w;
      acc[3][c] += h3.x * w4.x + h3.y * w4.y + h3.z * w4.z + h3.w * w4.w;
    }
  }

  float lse[4];
#pragma unroll
  for (int r = 0; r < 4; ++r) {
    float mx = acc[r][0];
#pragma unroll
    for (int c = 1; c < NCLS; ++c) mx = fmaxf(mx, acc[r][c]);
    float se = 0.f;
#pragma unroll
    for (int c = 0; c < NCLS; ++c) se += __expf(acc[r][c] - mx);
    lse[r] = mx + __logf(se);
  }
  const int b = r0 >> 9, s0 = r0 & 511;
#pragma unroll
  for (int c = 0; c < NCLS; ++c) {
    float4 o = make_float4(acc[0][c] - lse[0], acc[1][c] - lse[1],
                           acc[2][c] - lse[2], acc[3][c] - lse[3]);
    *(float4*)(out + (size_t)(b * NCLS + c) * SEQ + s0) = o;
  }
}

// ---------------- host ----------------
extern "C" void kernel_launch(void* const* d_in, const int* in_sizes, int n_in,
                              void* d_out, int out_size, void* d_ws, size_t ws_size,
                              hipStream_t stream) {
  const int*   inputs = (const int*)d_in[0];
  const float* emb    = (const float*)d_in[1];
  const float* w_ih   = (const float*)d_in[2];
  const float* w_hh   = (const float*)d_in[3];
  const float* b_ih   = (const float*)d_in[4];
  const float* b_hh   = (const float*)d_in[5];
  const float* w_lin  = (const float*)d_in[6];
  const float* b_lin  = (const float*)d_in[7];
  float* out = (float*)d_out;

  float* GI = (float*)d_ws;                    // 65536*300 f32 = 78.6 MB
  float* Hd = GI + (size_t)NROWS * G3;         // 65536*100 f32 = 26.2 MB

  uint32_t dk1a, dk1b, dk2a, dk2b;
  threefry2x32(0u, 42u, 0u, 0u, &dk1a, &dk1b);
  threefry2x32(0u, 42u, 0u, 1u, &dk2a, &dk2b);

  k_gi2<<<dim3(512, 3), 256, 0, stream>>>(inputs, emb, w_ih, b_ih, GI, dk1a, dk1b);
  k_rnn<<<BATCH, 192, 0, stream>>>(GI, w_hh, b_hh, Hd, dk2a, dk2b);
  k_out<<<256, 64, 0, stream>>>(Hd, w_lin, b_lin, out);
}

// Round 4
// 1027.822 us; speedup vs baseline: 1.0887x; 1.0257x over previous
//
#include <hip/hip_runtime.h>
#include <hip/hip_bf16.h>
#include <cstdint>

#define BATCH 128
#define SEQ   512
#define EMB   300
#define HID   100
#define G3    300
#define NCLS  20
#define NROWS (SEQ * BATCH)

// ---------------- threefry2x32 (JAX-compatible, verified round 1) ----------------
__host__ __device__ __forceinline__ void threefry2x32(uint32_t k0, uint32_t k1,
                                                      uint32_t x0, uint32_t x1,
                                                      uint32_t* o0, uint32_t* o1) {
  uint32_t ks2 = k0 ^ k1 ^ 0x1BD11BDAu;
  x0 += k0; x1 += k1;
#define TFR(r) { x0 += x1; x1 = (x1 << (r)) | (x1 >> (32 - (r))); x1 ^= x0; }
  TFR(13) TFR(15) TFR(26) TFR(6)  x0 += k1;  x1 += ks2 + 1u;
  TFR(17) TFR(29) TFR(16) TFR(24) x0 += ks2; x1 += k0 + 2u;
  TFR(13) TFR(15) TFR(26) TFR(6)  x0 += k0;  x1 += k1 + 3u;
  TFR(17) TFR(29) TFR(16) TFR(24) x0 += k1;  x1 += ks2 + 4u;
  TFR(13) TFR(15) TFR(26) TFR(6)  x0 += ks2; x1 += k0 + 5u;
#undef TFR
  *o0 = x0; *o1 = x1;
}

__device__ __forceinline__ uint32_t rand_bits32(uint32_t ka, uint32_t kb, uint32_t flat) {
  uint32_t a, b;
  threefry2x32(ka, kb, 0u, flat, &a, &b);
  return a ^ b;
}

// ---------------- K1: GI = dropout1(emb[idx]) @ w_ih^T + b_ih ----------------
// [unchanged from round 3 — passing]
__global__ __launch_bounds__(256) void k_gi2(const int* __restrict__ inputs,
                                             const float* __restrict__ emb,
                                             const float* __restrict__ w_ih,
                                             const float* __restrict__ b_ih,
                                             float* __restrict__ GI,
                                             uint32_t k1a, uint32_t k1b) {
  __shared__ float Xs[16][132];
  __shared__ float Ws[16][132];
  __shared__ int idxs[128];
  const int t = threadIdx.x;
  const int s = blockIdx.x;
  const int n0 = blockIdx.y * 128;
  const int tx = t & 15, ty = t >> 4;

  if (t < 128) idxs[t] = inputs[t * SEQ + s];

  float acc[8][8];
#pragma unroll
  for (int i = 0; i < 8; ++i)
#pragma unroll
    for (int j = 0; j < 8; ++j) acc[i][j] = 0.f;

  __syncthreads();

  for (int kc = 0; kc < 304; kc += 16) {
#pragma unroll
    for (int half = 0; half < 2; ++half) {
      int fi = t + half * 256;
      int row = fi >> 2;
      int kq = fi & 3;
      int e0 = kc + kq * 4;
      float4 xv = make_float4(0.f, 0.f, 0.f, 0.f);
      if (e0 < 300) {
        xv = *(const float4*)(emb + (size_t)idxs[row] * EMB + e0);
        uint32_t base = (uint32_t)((row * SEQ + s) * EMB + e0);
        xv.x = (rand_bits32(k1a, k1b, base + 0u) >> 31) ? 0.f : xv.x * 2.f;
        xv.y = (rand_bits32(k1a, k1b, base + 1u) >> 31) ? 0.f : xv.y * 2.f;
        xv.z = (rand_bits32(k1a, k1b, base + 2u) >> 31) ? 0.f : xv.z * 2.f;
        xv.w = (rand_bits32(k1a, k1b, base + 3u) >> 31) ? 0.f : xv.w * 2.f;
      }
      Xs[kq * 4 + 0][row] = xv.x;
      Xs[kq * 4 + 1][row] = xv.y;
      Xs[kq * 4 + 2][row] = xv.z;
      Xs[kq * 4 + 3][row] = xv.w;
      int n = n0 + row;
      float4 wv = make_float4(0.f, 0.f, 0.f, 0.f);
      if (e0 < 300 && n < 300) wv = *(const float4*)(w_ih + (size_t)n * EMB + e0);
      Ws[kq * 4 + 0][row] = wv.x;
      Ws[kq * 4 + 1][row] = wv.y;
      Ws[kq * 4 + 2][row] = wv.z;
      Ws[kq * 4 + 3][row] = wv.w;
    }
    __syncthreads();
#pragma unroll
    for (int k = 0; k < 16; ++k) {
      float4 xa = *(const float4*)&Xs[k][ty * 4];
      float4 xb = *(const float4*)&Xs[k][64 + ty * 4];
      float4 wa = *(const float4*)&Ws[k][tx * 4];
      float4 wb = *(const float4*)&Ws[k][64 + tx * 4];
      float xs8[8] = {xa.x, xa.y, xa.z, xa.w, xb.x, xb.y, xb.z, xb.w};
      float ws8[8] = {wa.x, wa.y, wa.z, wa.w, wb.x, wb.y, wb.z, wb.w};
#pragma unroll
      for (int i = 0; i < 8; ++i)
#pragma unroll
        for (int j = 0; j < 8; ++j) acc[i][j] = fmaf(xs8[i], ws8[j], acc[i][j]);
    }
    __syncthreads();
  }

#pragma unroll
  for (int i = 0; i < 8; ++i) {
    int m = (i < 4) ? (ty * 4 + i) : (64 + ty * 4 + (i - 4));
    size_t rbase = (size_t)(s * BATCH + m) * G3;
    int cA = n0 + tx * 4;
    int cB = n0 + 64 + tx * 4;
    if (cA < 300) {
      float4 o = make_float4(acc[i][0] + b_ih[cA], acc[i][1] + b_ih[cA + 1],
                             acc[i][2] + b_ih[cA + 2], acc[i][3] + b_ih[cA + 3]);
      *(float4*)(GI + rbase + cA) = o;
    }
    if (cB < 300) {
      float4 o = make_float4(acc[i][4] + b_ih[cB], acc[i][5] + b_ih[cB + 1],
                             acc[i][6] + b_ih[cB + 2], acc[i][7] + b_ih[cB + 3]);
      *(float4*)(GI + rbase + cB) = o;
    }
  }
}

// ---------------- K2: GRU recurrence v3 — weights in SSA float4s (no alloca/scratch) ----
// 128 blocks x 256 threads (4 waves). Wave-aligned k-split:
//   waves 0,1: k 0..51 (13 blocks); waves 2,3: k 52..99 (12 blocks).
//   wave 0/2: units 0..63; wave 1/3: units 64..99 (lanes 0..35).
// h kept ONLY in registers (hA=units 0-63, hB=64-99 per lane), broadcast via
// readlane with IMMEDIATE lane indices. Elementwise update done redundantly by
// every wave -> no h LDS round-trip. Partial dots meet through double-buffered
// LDS 'part' -> ONE barrier per step.
__global__ __launch_bounds__(256, 1) void k_rnn3(const float* __restrict__ GI,
                                                 const float* __restrict__ w_hh,
                                                 const float* __restrict__ b_hh,
                                                 float* __restrict__ Hd,
                                                 uint32_t k2a, uint32_t k2b) {
  __shared__ float4 part[2][2][104];   // [buf][half][unit] = (r,z,n,pad) partials
  const int t = threadIdx.x, lane = t & 63, wave = t >> 6;
  const int half = wave >> 1;                     // wave-uniform
  const int b = blockIdx.x;
  const int ulo = (lane < 36) ? lane : 35;
  const int uu = (wave & 1) ? (64 + ulo) : lane;  // unit whose 3 gate-rows this thread dots
  const bool wactive = ((wave & 1) == 0) || (lane < 36);
  const int uB = 64 + ulo;                        // second elementwise unit per lane

  const float* rowR = w_hh + (size_t)uu * HID;
  const float* rowZ = w_hh + (size_t)(uu + 100) * HID;
  const float* rowN = w_hh + (size_t)(uu + 200) * HID;
  const int kb = half ? 52 : 0;   // wave-uniform k base

#define LD4(p, off) (*(const float4*)((p) + (off)))
  // 39 float4 SSA values (156 VGPRs) — the whole point of this rewrite.
  float4 wr0 = LD4(rowR, kb +  0), wr1 = LD4(rowR, kb +  4), wr2  = LD4(rowR, kb +  8),
         wr3 = LD4(rowR, kb + 12), wr4 = LD4(rowR, kb + 16), wr5  = LD4(rowR, kb + 20),
         wr6 = LD4(rowR, kb + 24), wr7 = LD4(rowR, kb + 28), wr8  = LD4(rowR, kb + 32),
         wr9 = LD4(rowR, kb + 36), wr10 = LD4(rowR, kb + 40), wr11 = LD4(rowR, kb + 44),
         wr12 = LD4(rowR, 48);  // only used by half0 (k 48..51)
  float4 wz0 = LD4(rowZ, kb +  0), wz1 = LD4(rowZ, kb +  4), wz2  = LD4(rowZ, kb +  8),
         wz3 = LD4(rowZ, kb + 12), wz4 = LD4(rowZ, kb + 16), wz5  = LD4(rowZ, kb + 20),
         wz6 = LD4(rowZ, kb + 24), wz7 = LD4(rowZ, kb + 28), wz8  = LD4(rowZ, kb + 32),
         wz9 = LD4(rowZ, kb + 36), wz10 = LD4(rowZ, kb + 40), wz11 = LD4(rowZ, kb + 44),
         wz12 = LD4(rowZ, 48);
  float4 wn0 = LD4(rowN, kb +  0), wn1 = LD4(rowN, kb +  4), wn2  = LD4(rowN, kb +  8),
         wn3 = LD4(rowN, kb + 12), wn4 = LD4(rowN, kb + 16), wn5  = LD4(rowN, kb + 20),
         wn6 = LD4(rowN, kb + 24), wn7 = LD4(rowN, kb + 28), wn8  = LD4(rowN, kb + 32),
         wn9 = LD4(rowN, kb + 36), wn10 = LD4(rowN, kb + 40), wn11 = LD4(rowN, kb + 44),
         wn12 = LD4(rowN, 48);

  const float bRA = b_hh[lane], bZA = b_hh[100 + lane], bNA = b_hh[200 + lane];
  const float bRB = b_hh[uB],   bZB = b_hh[100 + uB],   bNB = b_hh[200 + uB];

  float hA = 0.f, hB = 0.f;   // units lane / 64+lane (hB valid lanes 0..35)

#define RL(reg, k) __int_as_float(__builtin_amdgcn_readlane(__float_as_int(reg), (k)))
#define BLK(i, K, HS) { \
    float h0 = RL(HS, (K) + 0), h1 = RL(HS, (K) + 1), h2 = RL(HS, (K) + 2), h3 = RL(HS, (K) + 3); \
    accr.x = fmaf(wr##i.x, h0, accr.x); accz.x = fmaf(wz##i.x, h0, accz.x); accn.x = fmaf(wn##i.x, h0, accn.x); \
    accr.y = fmaf(wr##i.y, h1, accr.y); accz.y = fmaf(wz##i.y, h1, accz.y); accn.y = fmaf(wn##i.y, h1, accn.y); \
    accr.z = fmaf(wr##i.z, h2, accr.z); accz.z = fmaf(wz##i.z, h2, accz.z); accn.z = fmaf(wn##i.z, h2, accn.z); \
    accr.w = fmaf(wr##i.w, h3, accr.w); accz.w = fmaf(wz##i.w, h3, accz.w); accn.w = fmaf(wn##i.w, h3, accn.w); \
  }

  for (int s = 0; s < SEQ; ++s) {
    // gi loads for the elementwise phase — issue before the dot to hide L3 latency
    const float* gp = GI + (size_t)(s * BATCH + b) * G3;
    float giRA = gp[lane], giZA = gp[100 + lane], giNA = gp[200 + lane];
    float giRB = gp[uB],   giZB = gp[100 + uB],   giNB = gp[200 + uB];

    float4 accr = make_float4(0.f, 0.f, 0.f, 0.f);
    float4 accz = make_float4(0.f, 0.f, 0.f, 0.f);
    float4 accn = make_float4(0.f, 0.f, 0.f, 0.f);
    if (half == 0) {   // wave-uniform branch; readlane indices are immediates
      BLK(0, 0, hA)  BLK(1, 4, hA)  BLK(2, 8, hA)  BLK(3, 12, hA)
      BLK(4, 16, hA) BLK(5, 20, hA) BLK(6, 24, hA) BLK(7, 28, hA)
      BLK(8, 32, hA) BLK(9, 36, hA) BLK(10, 40, hA) BLK(11, 44, hA)
      BLK(12, 48, hA)
    } else {           // k 52..99: 52,56,60 from hA; 64..96 from hB lanes 0..32
      BLK(0, 52, hA) BLK(1, 56, hA) BLK(2, 60, hA)
      BLK(3, 0, hB)  BLK(4, 4, hB)  BLK(5, 8, hB)  BLK(6, 12, hB)
      BLK(7, 16, hB) BLK(8, 20, hB) BLK(9, 24, hB) BLK(10, 28, hB)
      BLK(11, 32, hB)
    }
    float sR = (accr.x + accr.y) + (accr.z + accr.w);
    float sZ = (accz.x + accz.y) + (accz.z + accz.w);
    float sN = (accn.x + accn.y) + (accn.z + accn.w);
    const int buf = s & 1;
    if (wactive) part[buf][half][uu] = make_float4(sR, sZ, sN, 0.f);
    __syncthreads();   // the ONLY barrier per step (double-buffered part)

    float4 pA0 = part[buf][0][lane], pA1 = part[buf][1][lane];
    float4 pB0 = part[buf][0][uB],   pB1 = part[buf][1][uB];

    // ---- elementwise, set A (unit = lane), redundantly on every wave ----
    float hrA = pA0.x + pA1.x + bRA;
    float hzA = pA0.y + pA1.y + bZA;
    float hnA = pA0.z + pA1.z + bNA;
    float rA = 1.f / (1.f + __expf(-(giRA + hrA)));
    float zA = 1.f / (1.f + __expf(-(giZA + hzA)));
    float xnA = giNA + rA * hnA;
    float eA = __expf(2.f * fabsf(xnA));
    float nA = copysignf(1.f - 2.f / (eA + 1.f), xnA);
    float hnewA = (1.f - zA) * nA + zA * hA;
    uint32_t flA = (uint32_t)((s * BATCH + b) * HID + lane);
    float hdA = (rand_bits32(k2a, k2b, flA) >> 31) ? 0.f : hnewA * 2.f;

    // ---- elementwise, set B (unit = 64+lane, valid lanes 0..35) ----
    float hrB = pB0.x + pB1.x + bRB;
    float hzB = pB0.y + pB1.y + bZB;
    float hnB = pB0.z + pB1.z + bNB;
    float rB = 1.f / (1.f + __expf(-(giRB + hrB)));
    float zB = 1.f / (1.f + __expf(-(giZB + hzB)));
    float xnB = giNB + rB * hnB;
    float eB = __expf(2.f * fabsf(xnB));
    float nB = copysignf(1.f - 2.f / (eB + 1.f), xnB);
    float hnewB = (1.f - zB) * nB + zB * hB;
    uint32_t flB = (uint32_t)((s * BATCH + b) * HID + uB);
    float hdB = (rand_bits32(k2a, k2b, flB) >> 31) ? 0.f : hnewB * 2.f;

    if (wave == 0) {   // wave-uniform predicate; lone Hd writer
      float* hp = Hd + (size_t)(b * SEQ + s) * HID;
      hp[lane] = hdA;
      if (lane < 36) hp[uB] = hdB;
    }
    hA = hnewA;
    hB = hnewB;
  }
#undef BLK
#undef RL
#undef LD4
}

// ---------------- K3: logits + log_softmax [unchanged from round 3] ----------------
__global__ __launch_bounds__(64) void k_out(const float* __restrict__ Hd,
                                            const float* __restrict__ w_lin,
                                            const float* __restrict__ b_lin,
                                            float* __restrict__ out) {
  __shared__ float Wl[NCLS * HID];
  __shared__ float bl[NCLS];
  const int t = threadIdx.x;
  for (int i = t; i < NCLS * HID; i += 64) Wl[i] = w_lin[i];
  if (t < NCLS) bl[t] = b_lin[t];
  __syncthreads();

  const int r0 = (blockIdx.x * 64 + t) * 4;
  float acc[4][NCLS];
#pragma unroll
  for (int r = 0; r < 4; ++r)
#pragma unroll
    for (int c = 0; c < NCLS; ++c) acc[r][c] = bl[c];

  for (int k = 0; k < HID; k += 4) {
    float4 h0 = *(const float4*)(Hd + (size_t)(r0 + 0) * HID + k);
    float4 h1 = *(const float4*)(Hd + (size_t)(r0 + 1) * HID + k);
    float4 h2 = *(const float4*)(Hd + (size_t)(r0 + 2) * HID + k);
    float4 h3 = *(const float4*)(Hd + (size_t)(r0 + 3) * HID + k);
#pragma unroll
    for (int c = 0; c < NCLS; ++c) {
      float4 w4 = *(const float4*)&Wl[c * HID + k];
      acc[0][c] += h0.x * w4.x + h0.y * w4.y + h0.z * w4.z + h0.w * w4.w;
      acc[1][c] += h1.x * w4.x + h1.y * w4.y + h1.z * w4.z + h1.w * w4.w;
      acc[2][c] += h2.x * w4.x + h2.y * w4.y + h2.z * w4.z + h2.w * w4.w;
      acc[3][c] += h3.x * w4.x + h3.y * w4.y + h3.z * w4.z + h3.w * w4.w;
    }
  }

  float lse[4];
#pragma unroll
  for (int r = 0; r < 4; ++r) {
    float mx = acc[r][0];
#pragma unroll
    for (int c = 1; c < NCLS; ++c) mx = fmaxf(mx, acc[r][c]);
    float se = 0.f;
#pragma unroll
    for (int c = 0; c < NCLS; ++c) se += __expf(acc[r][c] - mx);
    lse[r] = mx + __logf(se);
  }
  const int b = r0 >> 9, s0 = r0 & 511;
#pragma unroll
  for (int c = 0; c < NCLS; ++c) {
    float4 o = make_float4(acc[0][c] - lse[0], acc[1][c] - lse[1],
                           acc[2][c] - lse[2], acc[3][c] - lse[3]);
    *(float4*)(out + (size_t)(b * NCLS + c) * SEQ + s0) = o;
  }
}

// ---------------- host ----------------
extern "C" void kernel_launch(void* const* d_in, const int* in_sizes, int n_in,
                              void* d_out, int out_size, void* d_ws, size_t ws_size,
                              hipStream_t stream) {
  const int*   inputs = (const int*)d_in[0];
  const float* emb    = (const float*)d_in[1];
  const float* w_ih   = (const float*)d_in[2];
  const float* w_hh   = (const float*)d_in[3];
  const float* b_ih   = (const float*)d_in[4];
  const float* b_hh   = (const float*)d_in[5];
  const float* w_lin  = (const float*)d_in[6];
  const float* b_lin  = (const float*)d_in[7];
  float* out = (float*)d_out;

  float* GI = (float*)d_ws;                    // 65536*300 f32 = 78.6 MB
  float* Hd = GI + (size_t)NROWS * G3;         // 65536*100 f32 = 26.2 MB

  uint32_t dk1a, dk1b, dk2a, dk2b;
  threefry2x32(0u, 42u, 0u, 0u, &dk1a, &dk1b);
  threefry2x32(0u, 42u, 0u, 1u, &dk2a, &dk2b);

  k_gi2<<<dim3(512, 3), 256, 0, stream>>>(inputs, emb, w_ih, b_ih, GI, dk1a, dk1b);
  k_rnn3<<<BATCH, 256, 0, stream>>>(GI, w_hh, b_hh, Hd, dk2a, dk2b);
  k_out<<<256, 64, 0, stream>>>(Hd, w_lin, b_lin, out);
}

// Round 5
// 961.482 us; speedup vs baseline: 1.1639x; 1.0690x over previous
//
#include <hip/hip_runtime.h>
#include <hip/hip_bf16.h>
#include <cstdint>

#define BATCH 128
#define SEQ   512
#define EMB   300
#define HID   100
#define G3    300
#define NCLS  20
#define NROWS (SEQ * BATCH)

// ---------------- threefry2x32 (JAX-compatible, verified round 1) ----------------
__host__ __device__ __forceinline__ void threefry2x32(uint32_t k0, uint32_t k1,
                                                      uint32_t x0, uint32_t x1,
                                                      uint32_t* o0, uint32_t* o1) {
  uint32_t ks2 = k0 ^ k1 ^ 0x1BD11BDAu;
  x0 += k0; x1 += k1;
#define TFR(r) { x0 += x1; x1 = (x1 << (r)) | (x1 >> (32 - (r))); x1 ^= x0; }
  TFR(13) TFR(15) TFR(26) TFR(6)  x0 += k1;  x1 += ks2 + 1u;
  TFR(17) TFR(29) TFR(16) TFR(24) x0 += ks2; x1 += k0 + 2u;
  TFR(13) TFR(15) TFR(26) TFR(6)  x0 += k0;  x1 += k1 + 3u;
  TFR(17) TFR(29) TFR(16) TFR(24) x0 += k1;  x1 += ks2 + 4u;
  TFR(13) TFR(15) TFR(26) TFR(6)  x0 += ks2; x1 += k0 + 5u;
#undef TFR
  *o0 = x0; *o1 = x1;
}

__device__ __forceinline__ uint32_t rand_bits32(uint32_t ka, uint32_t kb, uint32_t flat) {
  uint32_t a, b;
  threefry2x32(ka, kb, 0u, flat, &a, &b);
  return a ^ b;
}

// ---------------- K1: GI = dropout1(emb[idx]) @ w_ih^T + b_ih ----------------
// [unchanged — passing; will be attacked next round with its own counters]
__global__ __launch_bounds__(256) void k_gi2(const int* __restrict__ inputs,
                                             const float* __restrict__ emb,
                                             const float* __restrict__ w_ih,
                                             const float* __restrict__ b_ih,
                                             float* __restrict__ GI,
                                             uint32_t k1a, uint32_t k1b) {
  __shared__ float Xs[16][132];
  __shared__ float Ws[16][132];
  __shared__ int idxs[128];
  const int t = threadIdx.x;
  const int s = blockIdx.x;
  const int n0 = blockIdx.y * 128;
  const int tx = t & 15, ty = t >> 4;

  if (t < 128) idxs[t] = inputs[t * SEQ + s];

  float acc[8][8];
#pragma unroll
  for (int i = 0; i < 8; ++i)
#pragma unroll
    for (int j = 0; j < 8; ++j) acc[i][j] = 0.f;

  __syncthreads();

  for (int kc = 0; kc < 304; kc += 16) {
#pragma unroll
    for (int half = 0; half < 2; ++half) {
      int fi = t + half * 256;
      int row = fi >> 2;
      int kq = fi & 3;
      int e0 = kc + kq * 4;
      float4 xv = make_float4(0.f, 0.f, 0.f, 0.f);
      if (e0 < 300) {
        xv = *(const float4*)(emb + (size_t)idxs[row] * EMB + e0);
        uint32_t base = (uint32_t)((row * SEQ + s) * EMB + e0);
        xv.x = (rand_bits32(k1a, k1b, base + 0u) >> 31) ? 0.f : xv.x * 2.f;
        xv.y = (rand_bits32(k1a, k1b, base + 1u) >> 31) ? 0.f : xv.y * 2.f;
        xv.z = (rand_bits32(k1a, k1b, base + 2u) >> 31) ? 0.f : xv.z * 2.f;
        xv.w = (rand_bits32(k1a, k1b, base + 3u) >> 31) ? 0.f : xv.w * 2.f;
      }
      Xs[kq * 4 + 0][row] = xv.x;
      Xs[kq * 4 + 1][row] = xv.y;
      Xs[kq * 4 + 2][row] = xv.z;
      Xs[kq * 4 + 3][row] = xv.w;
      int n = n0 + row;
      float4 wv = make_float4(0.f, 0.f, 0.f, 0.f);
      if (e0 < 300 && n < 300) wv = *(const float4*)(w_ih + (size_t)n * EMB + e0);
      Ws[kq * 4 + 0][row] = wv.x;
      Ws[kq * 4 + 1][row] = wv.y;
      Ws[kq * 4 + 2][row] = wv.z;
      Ws[kq * 4 + 3][row] = wv.w;
    }
    __syncthreads();
#pragma unroll
    for (int k = 0; k < 16; ++k) {
      float4 xa = *(const float4*)&Xs[k][ty * 4];
      float4 xb = *(const float4*)&Xs[k][64 + ty * 4];
      float4 wa = *(const float4*)&Ws[k][tx * 4];
      float4 wb = *(const float4*)&Ws[k][64 + tx * 4];
      float xs8[8] = {xa.x, xa.y, xa.z, xa.w, xb.x, xb.y, xb.z, xb.w};
      float ws8[8] = {wa.x, wa.y, wa.z, wa.w, wb.x, wb.y, wb.z, wb.w};
#pragma unroll
      for (int i = 0; i < 8; ++i)
#pragma unroll
        for (int j = 0; j < 8; ++j) acc[i][j] = fmaf(xs8[i], ws8[j], acc[i][j]);
    }
    __syncthreads();
  }

#pragma unroll
  for (int i = 0; i < 8; ++i) {
    int m = (i < 4) ? (ty * 4 + i) : (64 + ty * 4 + (i - 4));
    size_t rbase = (size_t)(s * BATCH + m) * G3;
    int cA = n0 + tx * 4;
    int cB = n0 + 64 + tx * 4;
    if (cA < 300) {
      float4 o = make_float4(acc[i][0] + b_ih[cA], acc[i][1] + b_ih[cA + 1],
                             acc[i][2] + b_ih[cA + 2], acc[i][3] + b_ih[cA + 3]);
      *(float4*)(GI + rbase + cA) = o;
    }
    if (cB < 300) {
      float4 o = make_float4(acc[i][4] + b_ih[cB], acc[i][5] + b_ih[cB + 1],
                             acc[i][6] + b_ih[cB + 2], acc[i][7] + b_ih[cB + 3]);
      *(float4*)(GI + rbase + cB) = o;
    }
  }
}

// ---------------- K2 v4: 1024 threads, 39 resident weights/thread ----------------
// 16 waves: wave = (kslice q = wave>>1, unit-group g = wave&1).
//   g=0: unit u = lane (0..63); g=1: u = 64+lane (lanes 0..35 active for stores).
//   k-slices: q0..3 len 13 (lo 0,13,26,39), q4..7 len 12 (lo 52,64,76,88).
// Dot: h broadcast from registers hA (units 0..63) / hB (64..99) via readlane
// with compile-time lane immediates; straight-line for ALL threads.
// Partials -> part[q][u] LDS; barrier; waves 0..3 (lanes 0..24, 1 unit each)
// do gates+dropout+h update; barrier; all waves reload hA/hB from h_s.
__global__ __launch_bounds__(1024, 4) void k_rnn4(const float* __restrict__ GI,
                                                  const float* __restrict__ w_hh,
                                                  const float* __restrict__ b_hh,
                                                  float* __restrict__ Hd,
                                                  uint32_t k2a, uint32_t k2b) {
  __shared__ float4 part[8][104];   // [kslice][unit] = (r,z,n,pad); 13.3 KB
  __shared__ float h_s[100];
  const int t = threadIdx.x, lane = t & 63, wave = t >> 6;
  const int q = wave >> 1, g = wave & 1;
  const int b = blockIdx.x;
  const int ulo = (lane < 36) ? lane : 35;
  const int u = g ? (64 + ulo) : lane;              // this thread's dot unit
  const bool dotstore = (g == 0) || (lane < 36);
  const int klo = (q < 4) ? q * 13 : 52 + (q - 4) * 12;

  const float* rowR = w_hh + (size_t)u * HID;
  const float* rowZ = w_hh + (size_t)(u + 100) * HID;
  const float* rowN = w_hh + (size_t)(u + 200) * HID;
  // 39 named SSA scalars — small enough to stay resident at any occupancy.
  const float wr0 = rowR[klo + 0],  wr1 = rowR[klo + 1],  wr2 = rowR[klo + 2],
              wr3 = rowR[klo + 3],  wr4 = rowR[klo + 4],  wr5 = rowR[klo + 5],
              wr6 = rowR[klo + 6],  wr7 = rowR[klo + 7],  wr8 = rowR[klo + 8],
              wr9 = rowR[klo + 9],  wr10 = rowR[klo + 10], wr11 = rowR[klo + 11],
              wr12 = rowR[(klo + 12 < 100) ? (klo + 12) : 99];
  const float wz0 = rowZ[klo + 0],  wz1 = rowZ[klo + 1],  wz2 = rowZ[klo + 2],
              wz3 = rowZ[klo + 3],  wz4 = rowZ[klo + 4],  wz5 = rowZ[klo + 5],
              wz6 = rowZ[klo + 6],  wz7 = rowZ[klo + 7],  wz8 = rowZ[klo + 8],
              wz9 = rowZ[klo + 9],  wz10 = rowZ[klo + 10], wz11 = rowZ[klo + 11],
              wz12 = rowZ[(klo + 12 < 100) ? (klo + 12) : 99];
  const float wn0 = rowN[klo + 0],  wn1 = rowN[klo + 1],  wn2 = rowN[klo + 2],
              wn3 = rowN[klo + 3],  wn4 = rowN[klo + 4],  wn5 = rowN[klo + 5],
              wn6 = rowN[klo + 6],  wn7 = rowN[klo + 7],  wn8 = rowN[klo + 8],
              wn9 = rowN[klo + 9],  wn10 = rowN[klo + 10], wn11 = rowN[klo + 11],
              wn12 = rowN[(klo + 12 < 100) ? (klo + 12) : 99];

  // elementwise assignment: waves 0..3, one unit per lane (lanes 0..24)
  const bool ew = (wave < 4) && (lane < 25);
  const int ue = wave * 25 + lane;   // 0..99 when ew
  float bR = 0.f, bZ = 0.f, bN = 0.f, gcR = 0.f, gcZ = 0.f, gcN = 0.f;
  if (ew) {
    bR = b_hh[ue]; bZ = b_hh[100 + ue]; bN = b_hh[200 + ue];
    const float* g0 = GI + (size_t)(0 * BATCH + b) * G3;
    gcR = g0[ue]; gcZ = g0[100 + ue]; gcN = g0[200 + ue];
  }

  if (t < 100) h_s[t] = 0.f;
  float hA = 0.f, hB = 0.f;
  __syncthreads();

#define RL(reg, L) __int_as_float(__builtin_amdgcn_readlane(__float_as_int(reg), (L)))
#define S1(HS, L, WR, WZ, WN) { float hk = RL(HS, L); \
    sR = fmaf(WR, hk, sR); sZ = fmaf(WZ, hk, sZ); sN = fmaf(WN, hk, sN); }
#define D12(HS, L0) \
  S1(HS, (L0) + 0,  wr0,  wz0,  wn0)  S1(HS, (L0) + 1,  wr1,  wz1,  wn1)  \
  S1(HS, (L0) + 2,  wr2,  wz2,  wn2)  S1(HS, (L0) + 3,  wr3,  wz3,  wn3)  \
  S1(HS, (L0) + 4,  wr4,  wz4,  wn4)  S1(HS, (L0) + 5,  wr5,  wz5,  wn5)  \
  S1(HS, (L0) + 6,  wr6,  wz6,  wn6)  S1(HS, (L0) + 7,  wr7,  wz7,  wn7)  \
  S1(HS, (L0) + 8,  wr8,  wz8,  wn8)  S1(HS, (L0) + 9,  wr9,  wz9,  wn9)  \
  S1(HS, (L0) + 10, wr10, wz10, wn10) S1(HS, (L0) + 11, wr11, wz11, wn11)
#define D13(HS, L0) D12(HS, L0) S1(HS, (L0) + 12, wr12, wz12, wn12)

  for (int s = 0; s < SEQ; ++s) {
    // prefetch next step's gi (consumed next iteration -> full step of slack)
    float gnR = 0.f, gnZ = 0.f, gnN = 0.f;
    if (ew) {
      int sn = (s + 1 < SEQ) ? s + 1 : s;
      const float* gp = GI + (size_t)(sn * BATCH + b) * G3;
      gnR = gp[ue]; gnZ = gp[100 + ue]; gnN = gp[200 + ue];
    }

    float sR = 0.f, sZ = 0.f, sN = 0.f;
    switch (q) {   // wave-uniform; readlane lane indices are literals
      case 0: { D13(hA, 0)  } break;
      case 1: { D13(hA, 13) } break;
      case 2: { D13(hA, 26) } break;
      case 3: { D13(hA, 39) } break;
      case 4: { D12(hA, 52) } break;
      case 5: { D12(hB, 0)  } break;
      case 6: { D12(hB, 12) } break;
      case 7: { D12(hB, 24) } break;
    }
    if (dotstore) part[q][u] = make_float4(sR, sZ, sN, 0.f);
    __syncthreads();   // barrier 1: partials visible; h_s safe to overwrite

    if (wave < 4) {          // wave-uniform branch
      if (lane < 25) {       // lane-divergent, no cross-lane ops inside
        float4 p0 = part[0][ue], p1 = part[1][ue], p2 = part[2][ue], p3 = part[3][ue];
        float4 p4 = part[4][ue], p5 = part[5][ue], p6 = part[6][ue], p7 = part[7][ue];
        float hr = ((p0.x + p1.x) + (p2.x + p3.x)) + ((p4.x + p5.x) + (p6.x + p7.x)) + bR;
        float hz = ((p0.y + p1.y) + (p2.y + p3.y)) + ((p4.y + p5.y) + (p6.y + p7.y)) + bZ;
        float hn = ((p0.z + p1.z) + (p2.z + p3.z)) + ((p4.z + p5.z) + (p6.z + p7.z)) + bN;
        float r = 1.f / (1.f + __expf(-(gcR + hr)));
        float z = 1.f / (1.f + __expf(-(gcZ + hz)));
        float xn = gcN + r * hn;
        float e2 = __expf(2.f * fabsf(xn));
        float n = copysignf(1.f - 2.f / (e2 + 1.f), xn);   // overflow-safe tanh
        float hprev = h_s[ue];
        float hnew = (1.f - z) * n + z * hprev;
        uint32_t fl = (uint32_t)((s * BATCH + b) * HID + ue);
        float hd = (rand_bits32(k2a, k2b, fl) >> 31) ? 0.f : hnew * 2.f;
        Hd[(size_t)(b * SEQ + s) * HID + ue] = hd;
        h_s[ue] = hnew;
      }
    }
    __syncthreads();   // barrier 2: h_s updated
    hA = h_s[lane];                 // unconditional straight-line (readlane source)
    hB = h_s[64 + ulo];
    gcR = gnR; gcZ = gnZ; gcN = gnN;
  }
#undef D13
#undef D12
#undef S1
#undef RL
}

// ---------------- K3: logits + log_softmax [unchanged] ----------------
__global__ __launch_bounds__(64) void k_out(const float* __restrict__ Hd,
                                            const float* __restrict__ w_lin,
                                            const float* __restrict__ b_lin,
                                            float* __restrict__ out) {
  __shared__ float Wl[NCLS * HID];
  __shared__ float bl[NCLS];
  const int t = threadIdx.x;
  for (int i = t; i < NCLS * HID; i += 64) Wl[i] = w_lin[i];
  if (t < NCLS) bl[t] = b_lin[t];
  __syncthreads();

  const int r0 = (blockIdx.x * 64 + t) * 4;
  float acc[4][NCLS];
#pragma unroll
  for (int r = 0; r < 4; ++r)
#pragma unroll
    for (int c = 0; c < NCLS; ++c) acc[r][c] = bl[c];

  for (int k = 0; k < HID; k += 4) {
    float4 h0 = *(const float4*)(Hd + (size_t)(r0 + 0) * HID + k);
    float4 h1 = *(const float4*)(Hd + (size_t)(r0 + 1) * HID + k);
    float4 h2 = *(const float4*)(Hd + (size_t)(r0 + 2) * HID + k);
    float4 h3 = *(const float4*)(Hd + (size_t)(r0 + 3) * HID + k);
#pragma unroll
    for (int c = 0; c < NCLS; ++c) {
      float4 w4 = *(const float4*)&Wl[c * HID + k];
      acc[0][c] += h0.x * w4.x + h0.y * w4.y + h0.z * w4.z + h0.w * w4.w;
      acc[1][c] += h1.x * w4.x + h1.y * w4.y + h1.z * w4.z + h1.w * w4.w;
      acc[2][c] += h2.x * w4.x + h2.y * w4.y + h2.z * w4.z + h2.w * w4.w;
      acc[3][c] += h3.x * w4.x + h3.y * w4.y + h3.z * w4.z + h3.w * w4.w;
    }
  }

  float lse[4];
#pragma unroll
  for (int r = 0; r < 4; ++r) {
    float mx = acc[r][0];
#pragma unroll
    for (int c = 1; c < NCLS; ++c) mx = fmaxf(mx, acc[r][c]);
    float se = 0.f;
#pragma unroll
    for (int c = 0; c < NCLS; ++c) se += __expf(acc[r][c] - mx);
    lse[r] = mx + __logf(se);
  }
  const int b = r0 >> 9, s0 = r0 & 511;
#pragma unroll
  for (int c = 0; c < NCLS; ++c) {
    float4 o = make_float4(acc[0][c] - lse[0], acc[1][c] - lse[1],
                           acc[2][c] - lse[2], acc[3][c] - lse[3]);
    *(float4*)(out + (size_t)(b * NCLS + c) * SEQ + s0) = o;
  }
}

// ---------------- host ----------------
extern "C" void kernel_launch(void* const* d_in, const int* in_sizes, int n_in,
                              void* d_out, int out_size, void* d_ws, size_t ws_size,
                              hipStream_t stream) {
  const int*   inputs = (const int*)d_in[0];
  const float* emb    = (const float*)d_in[1];
  const float* w_ih   = (const float*)d_in[2];
  const float* w_hh   = (const float*)d_in[3];
  const float* b_ih   = (const float*)d_in[4];
  const float* b_hh   = (const float*)d_in[5];
  const float* w_lin  = (const float*)d_in[6];
  const float* b_lin  = (const float*)d_in[7];
  float* out = (float*)d_out;

  float* GI = (float*)d_ws;                    // 65536*300 f32 = 78.6 MB
  float* Hd = GI + (size_t)NROWS * G3;         // 65536*100 f32 = 26.2 MB

  uint32_t dk1a, dk1b, dk2a, dk2b;
  threefry2x32(0u, 42u, 0u, 0u, &dk1a, &dk1b);
  threefry2x32(0u, 42u, 0u, 1u, &dk2a, &dk2b);

  k_gi2<<<dim3(512, 3), 256, 0, stream>>>(inputs, emb, w_ih, b_ih, GI, dk1a, dk1b);
  k_rnn4<<<BATCH, 1024, 0, stream>>>(GI, w_hh, b_hh, Hd, dk2a, dk2b);
  k_out<<<256, 64, 0, stream>>>(Hd, w_lin, b_lin, out);
}